// Round 2
// baseline (257.092 us; speedup 1.0000x reference)
//
#include <hip/hip_runtime.h>
#include <math.h>

// Poincare fully-connected (hypll / Shimizu et al.), c = 1.
// B=1048576, IN=64, OUT=64, all fp32.
//
// Design: wave = 64-row tile, lane = row. x row in 64 VGPRs. z read as
// wave-uniform broadcast from a pre-transposed copy zT in d_ws (L1-resident).
// Per-o constants (cosh(2b)/||z||, sinh(2b), 2||z||) precomputed by hl_prep.
// ||x||^2 and sum(w^2) are in-lane accumulations (no cross-lane reduce).
// w[64] staged in XOR-swizzled LDS (conflict-free) -> coalesced 256B stores.

__global__ void hl_prep(const float* __restrict__ z, const float* __restrict__ bias,
                        float* __restrict__ ws) {
    const int o = threadIdx.x;  // 0..63
    float n2 = 0.f;
    #pragma unroll 8
    for (int k = 0; k < 64; ++k) {
        float v = z[k * 64 + o];
        ws[o * 64 + k] = v;            // zT[o][k]
        n2 = fmaf(v, v, n2);
    }
    const float zn = fmaxf(sqrtf(n2), 1e-15f);
    const float t = 2.f * bias[o];     // 2*sqrt(c)*bias, c=1
    const float e = expf(t);
    const float ei = 1.f / e;
    float4 c;
    c.x = 0.5f * (e + ei) / zn;        // K1 = cosh(2b)/zn
    c.y = 0.5f * (e - ei);             // K2 = sinh(2b)
    c.z = 2.f * zn;                    // K4 = 2*zn
    c.w = 0.f;
    reinterpret_cast<float4*>(ws + 4096)[o] = c;
}

template <bool PREP>
__global__ __launch_bounds__(256, 2)
void hl_main(const float* __restrict__ x, const float* __restrict__ z,
             const float* __restrict__ bias, const float* __restrict__ ws,
             float* __restrict__ out) {
    __shared__ float wbuf[4 * 64 * 64];          // 64 KiB: per-wave 64x64 w tile
    const int wave = threadIdx.x >> 6;
    const int lane = threadIdx.x & 63;           // = row within tile
    float* __restrict__ wb = wbuf + wave * 4096;
    const long tile = (long)blockIdx.x * 4 + wave;

    // ---- load own x row (64 floats) into registers ----
    const float* __restrict__ xrow = x + (tile * 64 + lane) * 64;
    float xs[64];
    #pragma unroll
    for (int i = 0; i < 16; ++i) {
        float4 f = reinterpret_cast<const float4*>(xrow)[i];
        xs[4*i+0] = f.x; xs[4*i+1] = f.y; xs[4*i+2] = f.z; xs[4*i+3] = f.w;
    }
    // ||x||^2 : in-lane
    float n0 = 0.f, n1 = 0.f, n2 = 0.f, n3 = 0.f;
    #pragma unroll
    for (int j = 0; j < 16; ++j) {
        n0 = fmaf(xs[4*j+0], xs[4*j+0], n0);
        n1 = fmaf(xs[4*j+1], xs[4*j+1], n1);
        n2 = fmaf(xs[4*j+2], xs[4*j+2], n2);
        n3 = fmaf(xs[4*j+3], xs[4*j+3], n3);
    }
    const float nx2 = (n0 + n1) + (n2 + n3);
    const float lam = 2.f * __builtin_amdgcn_rcpf(1.f - nx2);   // ||x|| <= 0.9

    float sw2 = 0.f;
    #pragma unroll 2
    for (int o = 0; o < 64; ++o) {
        float a0 = 0.f, a1 = 0.f, a2 = 0.f, a3 = 0.f;
        float K1, K2, K4;
        if (PREP) {
            const float4* __restrict__ zp = reinterpret_cast<const float4*>(ws + o * 64);
            #pragma unroll
            for (int j = 0; j < 16; ++j) {
                float4 zv = zp[j];                      // wave-uniform broadcast
                a0 = fmaf(xs[4*j+0], zv.x, a0);
                a1 = fmaf(xs[4*j+1], zv.y, a1);
                a2 = fmaf(xs[4*j+2], zv.z, a2);
                a3 = fmaf(xs[4*j+3], zv.w, a3);
            }
            const float4 c = reinterpret_cast<const float4*>(ws + 4096)[o];
            K1 = c.x; K2 = c.y; K4 = c.z;
        } else {
            // fallback when ws too small: read z row-major, derive consts inline
            float q0 = 0.f, q1 = 0.f, q2 = 0.f, q3 = 0.f;
            #pragma unroll
            for (int j = 0; j < 16; ++j) {
                float z0 = z[(4*j+0)*64 + o];
                float z1 = z[(4*j+1)*64 + o];
                float z2 = z[(4*j+2)*64 + o];
                float z3 = z[(4*j+3)*64 + o];
                a0 = fmaf(xs[4*j+0], z0, a0);
                a1 = fmaf(xs[4*j+1], z1, a1);
                a2 = fmaf(xs[4*j+2], z2, a2);
                a3 = fmaf(xs[4*j+3], z3, a3);
                q0 = fmaf(z0, z0, q0);
                q1 = fmaf(z1, z1, q1);
                q2 = fmaf(z2, z2, q2);
                q3 = fmaf(z3, z3, q3);
            }
            const float zn = fmaxf(__builtin_amdgcn_sqrtf((q0+q1)+(q2+q3)), 1e-15f);
            const float e2 = __builtin_amdgcn_exp2f(2.f * bias[o] * 1.4426950408889634f);
            const float e2i = __builtin_amdgcn_rcpf(e2);
            K1 = 0.5f * (e2 + e2i) * __builtin_amdgcn_rcpf(zn);
            K2 = 0.5f * (e2 - e2i);
            K4 = 2.f * zn;
        }
        const float xz = (a0 + a1) + (a2 + a3);
        // u = lam*xz*K1 - (lam-1)*K2  ==  lam*(xz*K1 - K2) + K2
        const float u  = fmaf(lam, fmaf(xz, K1, -K2), K2);
        const float au = fabsf(u);
        // asinh/sinh fused: t = |u|+sqrt(u^2+1); e^|v| = t^(2*zn) = exp2(K4*log2(t))
        const float sq = __builtin_amdgcn_sqrtf(fmaf(au, au, 1.f));
        const float lg = __builtin_amdgcn_logf(au + sq);      // log2
        const float e  = __builtin_amdgcn_exp2f(K4 * lg);     // 2^x
        const float einv = __builtin_amdgcn_rcpf(e);
        float w = fmaf(0.5f, e, -0.5f * einv);   // sinh(|v|) >= 0
        w = copysignf(w, u);                     // sinh odd
        sw2 = fmaf(w, w, sw2);                   // in-lane row accumulation
        wb[lane * 64 + (o ^ (lane & 31))] = w;   // swizzled, conflict-free
    }

    const float scale = __builtin_amdgcn_rcpf(1.f + __builtin_amdgcn_sqrtf(1.f + sw2));
    const int scale_i = __float_as_int(scale);
    float* __restrict__ orow = out + tile * 4096;
    // transpose via LDS -> fully coalesced 256B stores per iteration
    for (int i = 0; i < 64; ++i) {
        const float s = __int_as_float(__builtin_amdgcn_readlane(scale_i, i)); // row i's scale
        const float wv = wb[i * 64 + (lane ^ (i & 31))];                       // w[row i][o=lane]
        orow[i * 64 + lane] = wv * s;
    }
}

extern "C" void kernel_launch(void* const* d_in, const int* in_sizes, int n_in,
                              void* d_out, int out_size, void* d_ws, size_t ws_size,
                              hipStream_t stream) {
    const float* x    = (const float*)d_in[0];
    const float* z    = (const float*)d_in[1];
    const float* bias = (const float*)d_in[2];
    float* out = (float*)d_out;
    float* ws  = (float*)d_ws;

    const long rows   = (long)in_sizes[0] / 64;   // 1048576
    const int  blocks = (int)(rows / 256);        // 4 waves/block * 64 rows/wave

    if (ws_size >= (size_t)(4096 + 256) * sizeof(float)) {
        hl_prep<<<1, 64, 0, stream>>>(z, bias, ws);
        hl_main<true><<<blocks, 256, 0, stream>>>(x, z, bias, ws, out);
    } else {
        hl_main<false><<<blocks, 256, 0, stream>>>(x, z, bias, nullptr, out);
    }
}